// Round 4
// baseline (744.623 us; speedup 1.0000x reference)
//
#include <hip/hip_runtime.h>

#define N_NODES 50000
#define N_EDGES 800000
#define DIM 96
#define FEAT_ELEMS (N_NODES * DIM)

// ---------------------------------------------------------------------------
// bf16 helpers via raw bit ops
// ---------------------------------------------------------------------------
__device__ __forceinline__ float bf16_to_f32(unsigned short u) {
    unsigned int w = ((unsigned int)u) << 16;
    float f;
    __builtin_memcpy(&f, &w, 4);
    return f;
}
__device__ __forceinline__ unsigned short f32_to_bf16_rne(float f) {
    unsigned int w;
    __builtin_memcpy(&w, &f, 4);
    unsigned int r = (w + 0x7FFFu + ((w >> 16) & 1u)) >> 16;
    return (unsigned short)r;
}
// load element idx from a float buffer whose dtype is a runtime flag
__device__ __forceinline__ float ldv(const void* p, int isbf16, int idx) {
    if (isbf16) return bf16_to_f32(((const unsigned short*)p)[idx]);
    return ((const float*)p)[idx];
}

// ---------------------------------------------------------------------------
// detect edge dtype: int64 => odd 32-bit words (hi-words of values < 50000)
// are all zero; int32 => odd words are random node ids.  flagE=1 => int64
// ---------------------------------------------------------------------------
__global__ __launch_bounds__(64) void detect_edges_kernel(const unsigned int* edges,
                                                          int* flagE) {
    __shared__ unsigned int sh[64];
    int t = threadIdx.x;
    unsigned int acc = 0;
    for (int k = 0; k < 4; ++k) {
        int idx = t * 4 + k;           // 0..255
        int pos = 1 + 2 * idx * 3109;  // odd words, max 1,585,591 < 1.6M
        acc |= edges[pos];
    }
    sh[t] = acc;
    __syncthreads();
    if (t == 0) {
        unsigned int a = 0;
        for (int i = 0; i < 64; ++i) a |= sh[i];
        *flagE = (a == 0u) ? 1 : 0;
    }
}

// ---------------------------------------------------------------------------
// detect float dtype of x: bf16 words have bits14..7 = exponent of a N(0,1)
// value => in [100,135] essentially always; fp32 words have uniform mantissa
// bits there (~14% hit).  flagF=1 => bf16.  256 samples, threshold 128.
// ---------------------------------------------------------------------------
__global__ __launch_bounds__(256) void detect_feat_kernel(const unsigned int* x,
                                                          int* flagF) {
    __shared__ int sh[256];
    int t = threadIdx.x;
    unsigned int w = x[t * 9000];  // max 2,295,000 < 2.4M words (bf16 interp)
    unsigned int e = (w >> 7) & 0xFFu;
    sh[t] = (e >= 100u && e <= 135u) ? 1 : 0;
    __syncthreads();
    if (t == 0) {
        int c = 0;
        for (int i = 0; i < 256; ++i) c += sh[i];
        *flagF = (c >= 128) ? 1 : 0;
    }
}

__device__ __forceinline__ int edge_at(const void* ep, int is64, int idx) {
    if (is64) return (int)((const long long*)ep)[idx];
    return ((const int*)ep)[idx];
}

// ---------------------------------------------------------------------------
// degree / dinv
// ---------------------------------------------------------------------------
__global__ __launch_bounds__(256) void zero_deg_kernel(float* deg) {
    int i = blockIdx.x * 256 + threadIdx.x;
    if (i < N_NODES) deg[i] = 0.0f;
}
__global__ __launch_bounds__(256) void count_kernel(const void* edges, const int* flagE,
                                                    float* deg) {
    int e = blockIdx.x * 256 + threadIdx.x;
    if (e >= N_EDGES) return;
    int is64 = *flagE;
    int d = edge_at(edges, is64, N_EDGES + e);
    atomicAdd(&deg[d], 1.0f);
}
__global__ __launch_bounds__(256) void dinv_kernel(const float* deg, float* dinv) {
    int i = blockIdx.x * 256 + threadIdx.x;
    if (i < N_NODES) dinv[i] = rsqrtf(deg[i] + 1.0f);  // +1 self-loop
}

// ---------------------------------------------------------------------------
// agg[idx] = dinv[n]^2 * feat[idx]   (self-loop term; also zero-initializes)
// mode: 0=fp32, 1=bf16, 2=follow *flagF
// ---------------------------------------------------------------------------
__global__ __launch_bounds__(256) void init_agg_kernel(const void* feat,
                                                       const int* flagF, int mode,
                                                       const float* dinv, float* agg) {
    int idx = blockIdx.x * 256 + threadIdx.x;
    if (idx >= FEAT_ELEMS) return;
    int isbf16 = (mode == 2) ? *flagF : mode;
    int n = idx / DIM;
    float di = dinv[n];
    agg[idx] = di * di * ldv(feat, isbf16, idx);
}

// ---------------------------------------------------------------------------
// scatter: for edge e (src s -> dst d): agg[d,:] += dinv[s]*dinv[d]*feat[s,:]
// 32 lanes per edge, 3 dims per lane.
// ---------------------------------------------------------------------------
__global__ __launch_bounds__(256) void scatter_kernel(const void* feat,
                                                      const int* flagF, int mode,
                                                      const void* edges, const int* flagE,
                                                      const float* dinv, float* agg) {
    int gid = blockIdx.x * 256 + threadIdx.x;
    int e = gid >> 5;
    int lane = gid & 31;
    if (e >= N_EDGES) return;
    int isbf16 = (mode == 2) ? *flagF : mode;
    int is64 = *flagE;
    int s = edge_at(edges, is64, e);
    int d = edge_at(edges, is64, N_EDGES + e);
    float w = dinv[s] * dinv[d];
    int sb = s * DIM + lane;
    int db = d * DIM + lane;
    atomicAdd(&agg[db],      w * ldv(feat, isbf16, sb));
    atomicAdd(&agg[db + 32], w * ldv(feat, isbf16, sb + 32));
    atomicAdd(&agg[db + 64], w * ldv(feat, isbf16, sb + 64));
}

// ---------------------------------------------------------------------------
// GEMM + bias + ReLU: out[M,96] = relu(A[M,96] @ W[96,96] + b); A fp32.
// W/bias dtype follows *flagF; out dtype per outMode (0/1/2-follow-flagF).
// 256 threads: 8 col-groups x 12 cols, 32 row-groups x 4 rows => 128 rows/blk
// ---------------------------------------------------------------------------
__global__ __launch_bounds__(256) void gemm_bias_relu_kernel(const float* A,
                                                             const void* W, const void* bias,
                                                             const int* flagF,
                                                             void* out, int outMode) {
    __shared__ float Ws[DIM * DIM];
    __shared__ float bs[DIM];
    int wBf16 = *flagF;
    int outBf16 = (outMode == 2) ? wBf16 : outMode;
    for (int i = threadIdx.x; i < DIM * DIM; i += 256) Ws[i] = ldv(W, wBf16, i);
    if (threadIdx.x < DIM) bs[threadIdx.x] = ldv(bias, wBf16, threadIdx.x);
    __syncthreads();

    int colg = threadIdx.x & 7;   // 8 groups x 12 cols
    int rowg = threadIdx.x >> 3;  // 32 groups x 4 rows
    int row0 = blockIdx.x * 128 + rowg * 4;
    int c0 = colg * 12;

    float acc[4][12];
    for (int r = 0; r < 4; ++r)
        for (int j = 0; j < 12; ++j) acc[r][j] = 0.0f;

    for (int k = 0; k < DIM; k += 4) {
        float4 a[4];
        for (int r = 0; r < 4; ++r) {
            int row = row0 + r;
            a[r] = (row < N_NODES) ? *(const float4*)&A[row * DIM + k]
                                   : make_float4(0.f, 0.f, 0.f, 0.f);
        }
        for (int kk = 0; kk < 4; ++kk) {
            float w[12];
            for (int j = 0; j < 12; ++j) w[j] = Ws[(k + kk) * DIM + c0 + j];
            for (int r = 0; r < 4; ++r) {
                float av = (kk == 0) ? a[r].x : (kk == 1) ? a[r].y : (kk == 2) ? a[r].z : a[r].w;
                for (int j = 0; j < 12; ++j) acc[r][j] = fmaf(av, w[j], acc[r][j]);
            }
        }
    }

    for (int r = 0; r < 4; ++r) {
        int row = row0 + r;
        if (row >= N_NODES) continue;
        int ob = row * DIM + c0;
        for (int j = 0; j < 12; ++j) {
            float v = fmaxf(acc[r][j] + bs[c0 + j], 0.0f);
            if (outBf16) ((unsigned short*)out)[ob + j] = f32_to_bf16_rne(v);
            else         ((float*)out)[ob + j] = v;
        }
    }
}

// ---------------------------------------------------------------------------
extern "C" void kernel_launch(void* const* d_in, const int* in_sizes, int n_in,
                              void* d_out, int out_size, void* d_ws, size_t ws_size,
                              hipStream_t stream) {
    const void* x  = d_in[0];
    const void* ei = d_in[1];
    const void* W1 = d_in[2];
    const void* b1 = d_in[3];
    const void* W2 = d_in[4];
    const void* b2 = d_in[5];

    char* base = (char*)d_ws;
    size_t off = 0;
    int*   flagE = (int*)(base + off);   off += 256;
    int*   flagF = (int*)(base + off);   off += 256;
    float* deg   = (float*)(base + off); off += ((size_t)N_NODES * 4 + 255) & ~(size_t)255;
    float* dinv  = (float*)(base + off); off += ((size_t)N_NODES * 4 + 255) & ~(size_t)255;
    float* agg   = (float*)(base + off); off += ((size_t)FEAT_ELEMS * 4 + 255) & ~(size_t)255;
    // intermediate h: fp32 if workspace allows, else bf16 (function of ws_size only)
    int hBf16 = (ws_size != 0 && ws_size < off + (size_t)FEAT_ELEMS * 4 + 1024) ? 1 : 0;
    void* h = (void*)(base + off);

    const int ngrid = (N_NODES + 255) / 256;     // 196
    const int egrid = (N_EDGES + 255) / 256;     // 3125
    const int fgrid = (FEAT_ELEMS + 255) / 256;  // 18750
    const int sgrid = (N_EDGES * 32) / 256;      // 100000
    const int ggrid = (N_NODES + 127) / 128;     // 391

    detect_edges_kernel<<<1, 64, 0, stream>>>((const unsigned int*)ei, flagE);
    detect_feat_kernel<<<1, 256, 0, stream>>>((const unsigned int*)x, flagF);

    zero_deg_kernel<<<ngrid, 256, 0, stream>>>(deg);
    count_kernel<<<egrid, 256, 0, stream>>>(ei, flagE, deg);
    dinv_kernel<<<ngrid, 256, 0, stream>>>(deg, dinv);

    // ---- layer 1: agg = A_hat * x ; h = relu(agg @ W1 + b1) ----
    init_agg_kernel<<<fgrid, 256, 0, stream>>>(x, flagF, 2, dinv, agg);
    scatter_kernel<<<sgrid, 256, 0, stream>>>(x, flagF, 2, ei, flagE, dinv, agg);
    gemm_bias_relu_kernel<<<ggrid, 256, 0, stream>>>(agg, W1, b1, flagF, h, hBf16);

    // ---- layer 2: agg = A_hat * h ; out = relu(agg @ W2 + b2) ----
    init_agg_kernel<<<fgrid, 256, 0, stream>>>(h, flagF, hBf16, dinv, agg);
    scatter_kernel<<<sgrid, 256, 0, stream>>>(h, flagF, hBf16, ei, flagE, dinv, agg);
    gemm_bias_relu_kernel<<<ggrid, 256, 0, stream>>>(agg, W2, b2, flagF, d_out, 2);
}

// Round 5
// 525.166 us; speedup vs baseline: 1.4179x; 1.4179x over previous
//
#include <hip/hip_runtime.h>

#define N_NODES 50000
#define N_EDGES 800000
#define DIM 96
#define FEAT_ELEMS (N_NODES * DIM)

// ---------------------------------------------------------------------------
// bf16 helpers via raw bit ops
// ---------------------------------------------------------------------------
__device__ __forceinline__ float bf16_to_f32(unsigned short u) {
    unsigned int w = ((unsigned int)u) << 16;
    float f;
    __builtin_memcpy(&f, &w, 4);
    return f;
}
__device__ __forceinline__ unsigned short f32_to_bf16_rne(float f) {
    unsigned int w;
    __builtin_memcpy(&w, &f, 4);
    unsigned int r = (w + 0x7FFFu + ((w >> 16) & 1u)) >> 16;
    return (unsigned short)r;
}
__device__ __forceinline__ float ldv(const void* p, int isbf16, int idx) {
    if (isbf16) return bf16_to_f32(((const unsigned short*)p)[idx]);
    return ((const float*)p)[idx];
}

// ---------------------------------------------------------------------------
// detect edge dtype: int64 => odd 32-bit words are all zero.  flagE=1 => int64
// ---------------------------------------------------------------------------
__global__ __launch_bounds__(64) void detect_edges_kernel(const unsigned int* edges,
                                                          int* flagE) {
    __shared__ unsigned int sh[64];
    int t = threadIdx.x;
    unsigned int acc = 0;
    for (int k = 0; k < 4; ++k) {
        int idx = t * 4 + k;           // 0..255
        int pos = 1 + 2 * idx * 3109;  // odd words, max 1,585,591 < 1.6M
        acc |= edges[pos];
    }
    sh[t] = acc;
    __syncthreads();
    if (t == 0) {
        unsigned int a = 0;
        for (int i = 0; i < 64; ++i) a |= sh[i];
        *flagE = (a == 0u) ? 1 : 0;
    }
}

// ---------------------------------------------------------------------------
// detect float dtype of x (bf16 vs fp32) via exponent-field statistics.
// flagF=1 => bf16
// ---------------------------------------------------------------------------
__global__ __launch_bounds__(256) void detect_feat_kernel(const unsigned int* x,
                                                          int* flagF) {
    __shared__ int sh[256];
    int t = threadIdx.x;
    unsigned int w = x[t * 9000];  // max 2,295,000 < 2.4M words (bf16 interp)
    unsigned int e = (w >> 7) & 0xFFu;
    sh[t] = (e >= 100u && e <= 135u) ? 1 : 0;
    __syncthreads();
    if (t == 0) {
        int c = 0;
        for (int i = 0; i < 256; ++i) c += sh[i];
        *flagF = (c >= 128) ? 1 : 0;
    }
}

__device__ __forceinline__ int edge_at(const void* ep, int is64, int idx) {
    if (is64) return (int)((const long long*)ep)[idx];
    return ((const int*)ep)[idx];
}

// ---------------------------------------------------------------------------
// CSR build: count in-degree at dst, scan, fill
// ---------------------------------------------------------------------------
__global__ __launch_bounds__(256) void zero_cnt_kernel(int* cnt) {
    int i = blockIdx.x * 256 + threadIdx.x;
    if (i < N_NODES) cnt[i] = 0;
}
__global__ __launch_bounds__(256) void count_kernel(const void* edges, const int* flagE,
                                                    int* cnt) {
    int e = blockIdx.x * 256 + threadIdx.x;
    if (e >= N_EDGES) return;
    int is64 = *flagE;
    int d = edge_at(edges, is64, N_EDGES + e);
    atomicAdd(&cnt[d], 1);
}

// 256-thread single-block scan, low register pressure (re-reads cnt).
// Also emits cursor copy and dinv = rsqrt(deg+1).
__global__ __launch_bounds__(256) void scan_kernel(const int* cnt, int* row_ptr,
                                                   int* cursor, float* dinv) {
    __shared__ int sums[256];
    const int CH = 196;  // 256*196 = 50176 >= 50000
    int t = threadIdx.x;
    int base = t * CH;
    int local = 0;
    for (int j = 0; j < CH; ++j) {
        int idx = base + j;
        if (idx < N_NODES) local += cnt[idx];
    }
    sums[t] = local;
    __syncthreads();
    for (int off = 1; off < 256; off <<= 1) {
        int v = (t >= off) ? sums[t - off] : 0;
        __syncthreads();
        sums[t] += v;
        __syncthreads();
    }
    int prefix = sums[t] - local;  // exclusive prefix of this chunk
    for (int j = 0; j < CH; ++j) {
        int idx = base + j;
        if (idx < N_NODES) {
            int c = cnt[idx];
            row_ptr[idx] = prefix;
            cursor[idx]  = prefix;
            dinv[idx]    = rsqrtf((float)(c + 1));  // +1 self-loop
            prefix += c;
        }
    }
    if (t == 255) row_ptr[N_NODES] = sums[255];
}

__global__ __launch_bounds__(256) void fill_kernel(const void* edges, const int* flagE,
                                                   int* cursor, int* csr_src) {
    int e = blockIdx.x * 256 + threadIdx.x;
    if (e >= N_EDGES) return;
    int is64 = *flagE;
    int s = edge_at(edges, is64, e);
    int d = edge_at(edges, is64, N_EDGES + e);
    int pos = atomicAdd(&cursor[d], 1);
    csr_src[pos] = s;
}

// ---------------------------------------------------------------------------
// Gather-aggregate: agg[g,:] = dinv[g]^2*feat[g,:] + sum_{s in in(g)} dinv[s]*dinv[g]*feat[s,:]
// 32 lanes per node, 3 dims per lane, fp32 accumulation, edge loop unrolled x2.
// mode: 0=fp32, 1=bf16, 2=follow *flagF
// ---------------------------------------------------------------------------
__global__ __launch_bounds__(256) void gather_kernel(const void* feat,
                                                     const int* flagF, int mode,
                                                     const int* row_ptr, const int* csr_src,
                                                     const float* dinv, float* agg) {
    int gid = blockIdx.x * 256 + threadIdx.x;
    int g = gid >> 5;
    int lane = gid & 31;
    if (g >= N_NODES) return;
    int isbf16 = (mode == 2) ? *flagF : mode;
    float di = dinv[g];
    int gb = g * DIM + lane;
    float a0 = di * di * ldv(feat, isbf16, gb);
    float a1 = di * di * ldv(feat, isbf16, gb + 32);
    float a2 = di * di * ldv(feat, isbf16, gb + 64);
    int e = row_ptr[g], e1 = row_ptr[g + 1];
    for (; e + 2 <= e1; e += 2) {
        int s0 = csr_src[e];
        int s1 = csr_src[e + 1];
        float w0 = dinv[s0] * di;
        float w1 = dinv[s1] * di;
        int sb0 = s0 * DIM + lane;
        int sb1 = s1 * DIM + lane;
        float x00 = ldv(feat, isbf16, sb0);
        float x01 = ldv(feat, isbf16, sb0 + 32);
        float x02 = ldv(feat, isbf16, sb0 + 64);
        float x10 = ldv(feat, isbf16, sb1);
        float x11 = ldv(feat, isbf16, sb1 + 32);
        float x12 = ldv(feat, isbf16, sb1 + 64);
        a0 = fmaf(w0, x00, a0); a1 = fmaf(w0, x01, a1); a2 = fmaf(w0, x02, a2);
        a0 = fmaf(w1, x10, a0); a1 = fmaf(w1, x11, a1); a2 = fmaf(w1, x12, a2);
    }
    if (e < e1) {
        int s = csr_src[e];
        float w = dinv[s] * di;
        int sb = s * DIM + lane;
        a0 = fmaf(w, ldv(feat, isbf16, sb),      a0);
        a1 = fmaf(w, ldv(feat, isbf16, sb + 32), a1);
        a2 = fmaf(w, ldv(feat, isbf16, sb + 64), a2);
    }
    agg[gb]      = a0;
    agg[gb + 32] = a1;
    agg[gb + 64] = a2;
}

// ---------------------------------------------------------------------------
// GEMM + bias + ReLU: out[M,96] = relu(A[M,96] @ W[96,96] + b); A fp32.
// W/bias dtype follows *flagF; out dtype per outMode (0/1/2=follow flagF).
// ---------------------------------------------------------------------------
__global__ __launch_bounds__(256) void gemm_bias_relu_kernel(const float* A,
                                                             const void* W, const void* bias,
                                                             const int* flagF,
                                                             void* out, int outMode) {
    __shared__ float Ws[DIM * DIM];
    __shared__ float bs[DIM];
    int wBf16 = *flagF;
    int outBf16 = (outMode == 2) ? wBf16 : outMode;
    for (int i = threadIdx.x; i < DIM * DIM; i += 256) Ws[i] = ldv(W, wBf16, i);
    if (threadIdx.x < DIM) bs[threadIdx.x] = ldv(bias, wBf16, threadIdx.x);
    __syncthreads();

    int colg = threadIdx.x & 7;   // 8 groups x 12 cols
    int rowg = threadIdx.x >> 3;  // 32 groups x 4 rows
    int row0 = blockIdx.x * 128 + rowg * 4;
    int c0 = colg * 12;

    float acc[4][12];
    for (int r = 0; r < 4; ++r)
        for (int j = 0; j < 12; ++j) acc[r][j] = 0.0f;

    for (int k = 0; k < DIM; k += 4) {
        float4 a[4];
        for (int r = 0; r < 4; ++r) {
            int row = row0 + r;
            a[r] = (row < N_NODES) ? *(const float4*)&A[row * DIM + k]
                                   : make_float4(0.f, 0.f, 0.f, 0.f);
        }
        for (int kk = 0; kk < 4; ++kk) {
            float w[12];
            for (int j = 0; j < 12; ++j) w[j] = Ws[(k + kk) * DIM + c0 + j];
            for (int r = 0; r < 4; ++r) {
                float av = (kk == 0) ? a[r].x : (kk == 1) ? a[r].y : (kk == 2) ? a[r].z : a[r].w;
                for (int j = 0; j < 12; ++j) acc[r][j] = fmaf(av, w[j], acc[r][j]);
            }
        }
    }

    for (int r = 0; r < 4; ++r) {
        int row = row0 + r;
        if (row >= N_NODES) continue;
        int ob = row * DIM + c0;
        for (int j = 0; j < 12; ++j) {
            float v = fmaxf(acc[r][j] + bs[c0 + j], 0.0f);
            if (outBf16) ((unsigned short*)out)[ob + j] = f32_to_bf16_rne(v);
            else         ((float*)out)[ob + j] = v;
        }
    }
}

// ---------------------------------------------------------------------------
extern "C" void kernel_launch(void* const* d_in, const int* in_sizes, int n_in,
                              void* d_out, int out_size, void* d_ws, size_t ws_size,
                              hipStream_t stream) {
    const void* x  = d_in[0];
    const void* ei = d_in[1];
    const void* W1 = d_in[2];
    const void* b1 = d_in[3];
    const void* W2 = d_in[4];
    const void* b2 = d_in[5];

    char* base = (char*)d_ws;
    size_t off = 0;
    auto carve = [&](size_t bytes) -> void* {
        void* p = base + off;
        off += (bytes + 255) & ~(size_t)255;
        return p;
    };
    int*   flagE   = (int*)carve(4);
    int*   flagF   = (int*)carve(4);
    int*   cnt     = (int*)carve((size_t)N_NODES * 4);
    int*   cursor  = (int*)carve((size_t)N_NODES * 4);
    int*   row_ptr = (int*)carve((size_t)(N_NODES + 1) * 4);
    float* dinv    = (float*)carve((size_t)N_NODES * 4);
    int*   csr_src = (int*)carve((size_t)N_EDGES * 4);
    float* agg     = (float*)carve((size_t)FEAT_ELEMS * 4);
    // intermediate h: fp32 if workspace allows, else bf16 (function of ws_size only)
    int hBf16 = (ws_size != 0 && ws_size < off + (size_t)FEAT_ELEMS * 4 + 1024) ? 1 : 0;
    void* h = (void*)(base + off);

    const int ngrid = (N_NODES + 255) / 256;      // 196
    const int egrid = (N_EDGES + 255) / 256;      // 3125
    const int agrid = (N_NODES * 32 + 255) / 256; // 6250
    const int ggrid = (N_NODES + 127) / 128;      // 391

    detect_edges_kernel<<<1, 64, 0, stream>>>((const unsigned int*)ei, flagE);
    detect_feat_kernel<<<1, 256, 0, stream>>>((const unsigned int*)x, flagF);

    zero_cnt_kernel<<<ngrid, 256, 0, stream>>>(cnt);
    count_kernel<<<egrid, 256, 0, stream>>>(ei, flagE, cnt);
    scan_kernel<<<1, 256, 0, stream>>>(cnt, row_ptr, cursor, dinv);
    fill_kernel<<<egrid, 256, 0, stream>>>(ei, flagE, cursor, csr_src);

    // ---- layer 1: agg = A_hat * x ; h = relu(agg @ W1 + b1) ----
    gather_kernel<<<agrid, 256, 0, stream>>>(x, flagF, 2, row_ptr, csr_src, dinv, agg);
    gemm_bias_relu_kernel<<<ggrid, 256, 0, stream>>>(agg, W1, b1, flagF, h, hBf16);

    // ---- layer 2: agg = A_hat * h ; out = relu(agg @ W2 + b2) ----
    gather_kernel<<<agrid, 256, 0, stream>>>(h, flagF, hBf16, row_ptr, csr_src, dinv, agg);
    gemm_bias_relu_kernel<<<ggrid, 256, 0, stream>>>(agg, W2, b2, flagF, d_out, 2);
}

// Round 6
// 378.247 us; speedup vs baseline: 1.9686x; 1.3884x over previous
//
#include <hip/hip_runtime.h>

#define N_NODES 50000
#define N_EDGES 800000
#define DIM 96
#define FEAT_ELEMS (N_NODES * DIM)
#define NBLK 196  // ceil(50000/256)

// ---------------------------------------------------------------------------
// bf16 helpers via raw bit ops
// ---------------------------------------------------------------------------
__device__ __forceinline__ float bf16_to_f32(unsigned short u) {
    unsigned int w = ((unsigned int)u) << 16;
    float f;
    __builtin_memcpy(&f, &w, 4);
    return f;
}
__device__ __forceinline__ unsigned short f32_to_bf16_rne(float f) {
    unsigned int w;
    __builtin_memcpy(&w, &f, 4);
    unsigned int r = (w + 0x7FFFu + ((w >> 16) & 1u)) >> 16;
    return (unsigned short)r;
}
__device__ __forceinline__ float ldv(const void* p, int isbf16, int idx) {
    if (isbf16) return bf16_to_f32(((const unsigned short*)p)[idx]);
    return ((const float*)p)[idx];
}

// ---------------------------------------------------------------------------
// detect edge dtype: int64 => odd 32-bit words are all zero.  flagE=1 => int64
// ---------------------------------------------------------------------------
__global__ __launch_bounds__(64) void detect_edges_kernel(const unsigned int* edges,
                                                          int* flagE) {
    __shared__ unsigned int sh[64];
    int t = threadIdx.x;
    unsigned int acc = 0;
    for (int k = 0; k < 4; ++k) {
        int idx = t * 4 + k;           // 0..255
        int pos = 1 + 2 * idx * 3109;  // odd words, max 1,585,591 < 1.6M
        acc |= edges[pos];
    }
    sh[t] = acc;
    __syncthreads();
    if (t == 0) {
        unsigned int a = 0;
        for (int i = 0; i < 64; ++i) a |= sh[i];
        *flagE = (a == 0u) ? 1 : 0;
    }
}

// ---------------------------------------------------------------------------
// detect float dtype of x (bf16 vs fp32) via exponent-field statistics.
// flagF=1 => bf16
// ---------------------------------------------------------------------------
__global__ __launch_bounds__(256) void detect_feat_kernel(const unsigned int* x,
                                                          int* flagF) {
    __shared__ int sh[256];
    int t = threadIdx.x;
    unsigned int w = x[t * 9000];  // max 2,295,000 < 2.4M words (bf16 interp)
    unsigned int e = (w >> 7) & 0xFFu;
    sh[t] = (e >= 100u && e <= 135u) ? 1 : 0;
    __syncthreads();
    if (t == 0) {
        int c = 0;
        for (int i = 0; i < 256; ++i) c += sh[i];
        *flagF = (c >= 128) ? 1 : 0;
    }
}

__device__ __forceinline__ int edge_at(const void* ep, int is64, int idx) {
    if (is64) return (int)((const long long*)ep)[idx];
    return ((const int*)ep)[idx];
}

// ---------------------------------------------------------------------------
// CSR build: count in-degree at dst, 3-phase parallel scan, fill
// ---------------------------------------------------------------------------
__global__ __launch_bounds__(256) void zero_cnt_kernel(int* cnt) {
    int i = blockIdx.x * 256 + threadIdx.x;
    if (i < N_NODES) cnt[i] = 0;
}
__global__ __launch_bounds__(256) void count_kernel(const void* edges, const int* flagE,
                                                    int* cnt) {
    int e = blockIdx.x * 256 + threadIdx.x;
    if (e >= N_EDGES) return;
    int is64 = *flagE;
    int d = edge_at(edges, is64, N_EDGES + e);
    atomicAdd(&cnt[d], 1);
}

// phase A: per-block tree reduction of 256 counts -> blockSums[NBLK]
__global__ __launch_bounds__(256) void scan_blocksum_kernel(const int* cnt, int* blockSums) {
    __shared__ int sh[256];
    int i = blockIdx.x * 256 + threadIdx.x;
    sh[threadIdx.x] = (i < N_NODES) ? cnt[i] : 0;
    __syncthreads();
    for (int off = 128; off > 0; off >>= 1) {
        if (threadIdx.x < off) sh[threadIdx.x] += sh[threadIdx.x + off];
        __syncthreads();
    }
    if (threadIdx.x == 0) blockSums[blockIdx.x] = sh[0];
}

// phase B: one block scans the NBLK partials -> exclusive blockOffs + total
__global__ __launch_bounds__(256) void scan_offsets_kernel(const int* blockSums,
                                                           int* blockOffs, int* row_ptr) {
    __shared__ int sh[256];
    int t = threadIdx.x;
    int v = (t < NBLK) ? blockSums[t] : 0;
    sh[t] = v;
    __syncthreads();
    for (int off = 1; off < 256; off <<= 1) {
        int u = (t >= off) ? sh[t - off] : 0;
        __syncthreads();
        sh[t] += u;
        __syncthreads();
    }
    if (t < NBLK) blockOffs[t] = sh[t] - v;  // exclusive
    if (t == 255) row_ptr[N_NODES] = sh[255];
}

// phase C: per-block local scan + block offset -> row_ptr/cursor/dinv
__global__ __launch_bounds__(256) void scan_apply_kernel(const int* cnt, const int* blockOffs,
                                                         int* row_ptr, int* cursor,
                                                         float* dinv) {
    __shared__ int sh[256];
    int t = threadIdx.x;
    int i = blockIdx.x * 256 + t;
    int c = (i < N_NODES) ? cnt[i] : 0;
    sh[t] = c;
    __syncthreads();
    for (int off = 1; off < 256; off <<= 1) {
        int u = (t >= off) ? sh[t - off] : 0;
        __syncthreads();
        sh[t] += u;
        __syncthreads();
    }
    if (i < N_NODES) {
        int excl = sh[t] - c + blockOffs[blockIdx.x];
        row_ptr[i] = excl;
        cursor[i]  = excl;
        dinv[i]    = rsqrtf((float)(c + 1));  // +1 self-loop
    }
}

__global__ __launch_bounds__(256) void fill_kernel(const void* edges, const int* flagE,
                                                   int* cursor, int* csr_src) {
    int e = blockIdx.x * 256 + threadIdx.x;
    if (e >= N_EDGES) return;
    int is64 = *flagE;
    int s = edge_at(edges, is64, e);
    int d = edge_at(edges, is64, N_EDGES + e);
    int pos = atomicAdd(&cursor[d], 1);
    csr_src[pos] = s;
}

// ---------------------------------------------------------------------------
// Gather-aggregate: agg[g,:] = dinv[g]^2*feat[g,:] + sum_{s in in(g)} dinv[s]*dinv[g]*feat[s,:]
// 32 lanes per node, 3 dims per lane, fp32 accumulation, edge loop unrolled x2.
// mode: 0=fp32, 1=bf16, 2=follow *flagF
// ---------------------------------------------------------------------------
__global__ __launch_bounds__(256) void gather_kernel(const void* feat,
                                                     const int* flagF, int mode,
                                                     const int* row_ptr, const int* csr_src,
                                                     const float* dinv, float* agg) {
    int gid = blockIdx.x * 256 + threadIdx.x;
    int g = gid >> 5;
    int lane = gid & 31;
    if (g >= N_NODES) return;
    int isbf16 = (mode == 2) ? *flagF : mode;
    float di = dinv[g];
    int gb = g * DIM + lane;
    float a0 = di * di * ldv(feat, isbf16, gb);
    float a1 = di * di * ldv(feat, isbf16, gb + 32);
    float a2 = di * di * ldv(feat, isbf16, gb + 64);
    int e = row_ptr[g], e1 = row_ptr[g + 1];
    for (; e + 2 <= e1; e += 2) {
        int s0 = csr_src[e];
        int s1 = csr_src[e + 1];
        float w0 = dinv[s0] * di;
        float w1 = dinv[s1] * di;
        int sb0 = s0 * DIM + lane;
        int sb1 = s1 * DIM + lane;
        float x00 = ldv(feat, isbf16, sb0);
        float x01 = ldv(feat, isbf16, sb0 + 32);
        float x02 = ldv(feat, isbf16, sb0 + 64);
        float x10 = ldv(feat, isbf16, sb1);
        float x11 = ldv(feat, isbf16, sb1 + 32);
        float x12 = ldv(feat, isbf16, sb1 + 64);
        a0 = fmaf(w0, x00, a0); a1 = fmaf(w0, x01, a1); a2 = fmaf(w0, x02, a2);
        a0 = fmaf(w1, x10, a0); a1 = fmaf(w1, x11, a1); a2 = fmaf(w1, x12, a2);
    }
    if (e < e1) {
        int s = csr_src[e];
        float w = dinv[s] * di;
        int sb = s * DIM + lane;
        a0 = fmaf(w, ldv(feat, isbf16, sb),      a0);
        a1 = fmaf(w, ldv(feat, isbf16, sb + 32), a1);
        a2 = fmaf(w, ldv(feat, isbf16, sb + 64), a2);
    }
    agg[gb]      = a0;
    agg[gb + 32] = a1;
    agg[gb + 64] = a2;
}

// ---------------------------------------------------------------------------
// GEMM + bias + ReLU: out[M,96] = relu(A[M,96] @ W[96,96] + b); A fp32.
// W/bias dtype follows *flagF; out dtype per outMode (0/1/2=follow flagF).
// ---------------------------------------------------------------------------
__global__ __launch_bounds__(256) void gemm_bias_relu_kernel(const float* A,
                                                             const void* W, const void* bias,
                                                             const int* flagF,
                                                             void* out, int outMode) {
    __shared__ float Ws[DIM * DIM];
    __shared__ float bs[DIM];
    int wBf16 = *flagF;
    int outBf16 = (outMode == 2) ? wBf16 : outMode;
    for (int i = threadIdx.x; i < DIM * DIM; i += 256) Ws[i] = ldv(W, wBf16, i);
    if (threadIdx.x < DIM) bs[threadIdx.x] = ldv(bias, wBf16, threadIdx.x);
    __syncthreads();

    int colg = threadIdx.x & 7;   // 8 groups x 12 cols
    int rowg = threadIdx.x >> 3;  // 32 groups x 4 rows
    int row0 = blockIdx.x * 128 + rowg * 4;
    int c0 = colg * 12;

    float acc[4][12];
    for (int r = 0; r < 4; ++r)
        for (int j = 0; j < 12; ++j) acc[r][j] = 0.0f;

    for (int k = 0; k < DIM; k += 4) {
        float4 a[4];
        for (int r = 0; r < 4; ++r) {
            int row = row0 + r;
            a[r] = (row < N_NODES) ? *(const float4*)&A[row * DIM + k]
                                   : make_float4(0.f, 0.f, 0.f, 0.f);
        }
        for (int kk = 0; kk < 4; ++kk) {
            float w[12];
            for (int j = 0; j < 12; ++j) w[j] = Ws[(k + kk) * DIM + c0 + j];
            for (int r = 0; r < 4; ++r) {
                float av = (kk == 0) ? a[r].x : (kk == 1) ? a[r].y : (kk == 2) ? a[r].z : a[r].w;
                for (int j = 0; j < 12; ++j) acc[r][j] = fmaf(av, w[j], acc[r][j]);
            }
        }
    }

    for (int r = 0; r < 4; ++r) {
        int row = row0 + r;
        if (row >= N_NODES) continue;
        int ob = row * DIM + c0;
        for (int j = 0; j < 12; ++j) {
            float v = fmaxf(acc[r][j] + bs[c0 + j], 0.0f);
            if (outBf16) ((unsigned short*)out)[ob + j] = f32_to_bf16_rne(v);
            else         ((float*)out)[ob + j] = v;
        }
    }
}

// ---------------------------------------------------------------------------
extern "C" void kernel_launch(void* const* d_in, const int* in_sizes, int n_in,
                              void* d_out, int out_size, void* d_ws, size_t ws_size,
                              hipStream_t stream) {
    const void* x  = d_in[0];
    const void* ei = d_in[1];
    const void* W1 = d_in[2];
    const void* b1 = d_in[3];
    const void* W2 = d_in[4];
    const void* b2 = d_in[5];

    char* base = (char*)d_ws;
    size_t off = 0;
    auto carve = [&](size_t bytes) -> void* {
        void* p = base + off;
        off += (bytes + 255) & ~(size_t)255;
        return p;
    };
    int*   flagE     = (int*)carve(4);
    int*   flagF     = (int*)carve(4);
    int*   cnt       = (int*)carve((size_t)N_NODES * 4);
    int*   cursor    = (int*)carve((size_t)N_NODES * 4);
    int*   row_ptr   = (int*)carve((size_t)(N_NODES + 1) * 4);
    float* dinv      = (float*)carve((size_t)N_NODES * 4);
    int*   blockSums = (int*)carve((size_t)NBLK * 4);
    int*   blockOffs = (int*)carve((size_t)NBLK * 4);
    int*   csr_src   = (int*)carve((size_t)N_EDGES * 4);
    float* agg       = (float*)carve((size_t)FEAT_ELEMS * 4);
    // intermediate h: fp32 if workspace allows, else bf16 (function of ws_size only)
    int hBf16 = (ws_size != 0 && ws_size < off + (size_t)FEAT_ELEMS * 4 + 1024) ? 1 : 0;
    void* h = (void*)(base + off);

    const int ngrid = NBLK;                        // 196
    const int egrid = (N_EDGES + 255) / 256;       // 3125
    const int agrid = (N_NODES * 32 + 255) / 256;  // 6250
    const int ggrid = (N_NODES + 127) / 128;       // 391

    detect_edges_kernel<<<1, 64, 0, stream>>>((const unsigned int*)ei, flagE);
    detect_feat_kernel<<<1, 256, 0, stream>>>((const unsigned int*)x, flagF);

    zero_cnt_kernel<<<ngrid, 256, 0, stream>>>(cnt);
    count_kernel<<<egrid, 256, 0, stream>>>(ei, flagE, cnt);
    scan_blocksum_kernel<<<ngrid, 256, 0, stream>>>(cnt, blockSums);
    scan_offsets_kernel<<<1, 256, 0, stream>>>(blockSums, blockOffs, row_ptr);
    scan_apply_kernel<<<ngrid, 256, 0, stream>>>(cnt, blockOffs, row_ptr, cursor, dinv);
    fill_kernel<<<egrid, 256, 0, stream>>>(ei, flagE, cursor, csr_src);

    // ---- layer 1: agg = A_hat * x ; h = relu(agg @ W1 + b1) ----
    gather_kernel<<<agrid, 256, 0, stream>>>(x, flagF, 2, row_ptr, csr_src, dinv, agg);
    gemm_bias_relu_kernel<<<ggrid, 256, 0, stream>>>(agg, W1, b1, flagF, h, hBf16);

    // ---- layer 2: agg = A_hat * h ; out = relu(agg @ W2 + b2) ----
    gather_kernel<<<agrid, 256, 0, stream>>>(h, flagF, hBf16, row_ptr, csr_src, dinv, agg);
    gemm_bias_relu_kernel<<<ggrid, 256, 0, stream>>>(agg, W2, b2, flagF, d_out, 2);
}

// Round 7
// 322.311 us; speedup vs baseline: 2.3103x; 1.1735x over previous
//
#include <hip/hip_runtime.h>

#define N_NODES 50000
#define N_EDGES 800000
#define DIM 96
#define FEAT_ELEMS (N_NODES * DIM)
#define NBLK 196  // ceil(50000/256)

// ---------------------------------------------------------------------------
// bf16 helpers via raw bit ops
// ---------------------------------------------------------------------------
__device__ __forceinline__ float bf16_to_f32(unsigned short u) {
    unsigned int w = ((unsigned int)u) << 16;
    float f;
    __builtin_memcpy(&f, &w, 4);
    return f;
}
__device__ __forceinline__ unsigned short f32_to_bf16_rne(float f) {
    unsigned int w;
    __builtin_memcpy(&w, &f, 4);
    unsigned int r = (w + 0x7FFFu + ((w >> 16) & 1u)) >> 16;
    return (unsigned short)r;
}
__device__ __forceinline__ float ldv(const void* p, int isbf16, int idx) {
    if (isbf16) return bf16_to_f32(((const unsigned short*)p)[idx]);
    return ((const float*)p)[idx];
}

// ---------------------------------------------------------------------------
// detect edge dtype: int64 => odd 32-bit words are all zero.  flagE=1 => int64
// ---------------------------------------------------------------------------
__global__ __launch_bounds__(64) void detect_edges_kernel(const unsigned int* edges,
                                                          int* flagE) {
    __shared__ unsigned int sh[64];
    int t = threadIdx.x;
    unsigned int acc = 0;
    for (int k = 0; k < 4; ++k) {
        int idx = t * 4 + k;           // 0..255
        int pos = 1 + 2 * idx * 3109;  // odd words, max 1,585,591 < 1.6M
        acc |= edges[pos];
    }
    sh[t] = acc;
    __syncthreads();
    if (t == 0) {
        unsigned int a = 0;
        for (int i = 0; i < 64; ++i) a |= sh[i];
        *flagE = (a == 0u) ? 1 : 0;
    }
}

// ---------------------------------------------------------------------------
// detect float dtype of x (bf16 vs fp32) via exponent-field statistics.
// flagF=1 => bf16
// ---------------------------------------------------------------------------
__global__ __launch_bounds__(256) void detect_feat_kernel(const unsigned int* x,
                                                          int* flagF) {
    __shared__ int sh[256];
    int t = threadIdx.x;
    unsigned int w = x[t * 9000];  // max 2,295,000 < 2.4M words (bf16 interp)
    unsigned int e = (w >> 7) & 0xFFu;
    sh[t] = (e >= 100u && e <= 135u) ? 1 : 0;
    __syncthreads();
    if (t == 0) {
        int c = 0;
        for (int i = 0; i < 256; ++i) c += sh[i];
        *flagF = (c >= 128) ? 1 : 0;
    }
}

__device__ __forceinline__ int edge_at(const void* ep, int is64, int idx) {
    if (is64) return (int)((const long long*)ep)[idx];
    return ((const int*)ep)[idx];
}

// ---------------------------------------------------------------------------
// CSR build: count in-degree at dst, 3-phase parallel scan, fill
// ---------------------------------------------------------------------------
__global__ __launch_bounds__(256) void zero_cnt_kernel(int* cnt) {
    int i = blockIdx.x * 256 + threadIdx.x;
    if (i < N_NODES) cnt[i] = 0;
}
__global__ __launch_bounds__(256) void count_kernel(const void* edges, const int* flagE,
                                                    int* cnt) {
    int e = blockIdx.x * 256 + threadIdx.x;
    if (e >= N_EDGES) return;
    int is64 = *flagE;
    int d = edge_at(edges, is64, N_EDGES + e);
    atomicAdd(&cnt[d], 1);
}

// phase A: per-block tree reduction of 256 counts -> blockSums[NBLK]
__global__ __launch_bounds__(256) void scan_blocksum_kernel(const int* cnt, int* blockSums) {
    __shared__ int sh[256];
    int i = blockIdx.x * 256 + threadIdx.x;
    sh[threadIdx.x] = (i < N_NODES) ? cnt[i] : 0;
    __syncthreads();
    for (int off = 128; off > 0; off >>= 1) {
        if (threadIdx.x < off) sh[threadIdx.x] += sh[threadIdx.x + off];
        __syncthreads();
    }
    if (threadIdx.x == 0) blockSums[blockIdx.x] = sh[0];
}

// phase B: one block scans the NBLK partials -> exclusive blockOffs + total
__global__ __launch_bounds__(256) void scan_offsets_kernel(const int* blockSums,
                                                           int* blockOffs, int* row_ptr) {
    __shared__ int sh[256];
    int t = threadIdx.x;
    int v = (t < NBLK) ? blockSums[t] : 0;
    sh[t] = v;
    __syncthreads();
    for (int off = 1; off < 256; off <<= 1) {
        int u = (t >= off) ? sh[t - off] : 0;
        __syncthreads();
        sh[t] += u;
        __syncthreads();
    }
    if (t < NBLK) blockOffs[t] = sh[t] - v;  // exclusive
    if (t == 255) row_ptr[N_NODES] = sh[255];
}

// phase C: per-block local scan + block offset -> row_ptr/cursor/dinv
__global__ __launch_bounds__(256) void scan_apply_kernel(const int* cnt, const int* blockOffs,
                                                         int* row_ptr, int* cursor,
                                                         float* dinv) {
    __shared__ int sh[256];
    int t = threadIdx.x;
    int i = blockIdx.x * 256 + t;
    int c = (i < N_NODES) ? cnt[i] : 0;
    sh[t] = c;
    __syncthreads();
    for (int off = 1; off < 256; off <<= 1) {
        int u = (t >= off) ? sh[t - off] : 0;
        __syncthreads();
        sh[t] += u;
        __syncthreads();
    }
    if (i < N_NODES) {
        int excl = sh[t] - c + blockOffs[blockIdx.x];
        row_ptr[i] = excl;
        cursor[i]  = excl;
        dinv[i]    = rsqrtf((float)(c + 1));  // +1 self-loop
    }
}

__global__ __launch_bounds__(256) void fill_kernel(const void* edges, const int* flagE,
                                                   int* cursor, int* csr_src) {
    int e = blockIdx.x * 256 + threadIdx.x;
    if (e >= N_EDGES) return;
    int is64 = *flagE;
    int s = edge_at(edges, is64, e);
    int d = edge_at(edges, is64, N_EDGES + e);
    int pos = atomicAdd(&cursor[d], 1);
    csr_src[pos] = s;
}

// ---------------------------------------------------------------------------
// Gather-aggregate: agg[g,:] = dinv[g]^2*feat[g,:] + sum_{s in in(g)} dinv[s]*dinv[g]*feat[s,:]
// 32 lanes per node, 3 dims per lane, fp32 accumulation, edge loop unrolled x2.
// mode: 0=fp32, 1=bf16, 2=follow *flagF
// ---------------------------------------------------------------------------
__global__ __launch_bounds__(256) void gather_kernel(const void* feat,
                                                     const int* flagF, int mode,
                                                     const int* row_ptr, const int* csr_src,
                                                     const float* dinv, float* agg) {
    int gid = blockIdx.x * 256 + threadIdx.x;
    int g = gid >> 5;
    int lane = gid & 31;
    if (g >= N_NODES) return;
    int isbf16 = (mode == 2) ? *flagF : mode;
    float di = dinv[g];
    int gb = g * DIM + lane;
    float a0 = di * di * ldv(feat, isbf16, gb);
    float a1 = di * di * ldv(feat, isbf16, gb + 32);
    float a2 = di * di * ldv(feat, isbf16, gb + 64);
    int e = row_ptr[g], e1 = row_ptr[g + 1];
    for (; e + 2 <= e1; e += 2) {
        int s0 = csr_src[e];
        int s1 = csr_src[e + 1];
        float w0 = dinv[s0] * di;
        float w1 = dinv[s1] * di;
        int sb0 = s0 * DIM + lane;
        int sb1 = s1 * DIM + lane;
        float x00 = ldv(feat, isbf16, sb0);
        float x01 = ldv(feat, isbf16, sb0 + 32);
        float x02 = ldv(feat, isbf16, sb0 + 64);
        float x10 = ldv(feat, isbf16, sb1);
        float x11 = ldv(feat, isbf16, sb1 + 32);
        float x12 = ldv(feat, isbf16, sb1 + 64);
        a0 = fmaf(w0, x00, a0); a1 = fmaf(w0, x01, a1); a2 = fmaf(w0, x02, a2);
        a0 = fmaf(w1, x10, a0); a1 = fmaf(w1, x11, a1); a2 = fmaf(w1, x12, a2);
    }
    if (e < e1) {
        int s = csr_src[e];
        float w = dinv[s] * di;
        int sb = s * DIM + lane;
        a0 = fmaf(w, ldv(feat, isbf16, sb),      a0);
        a1 = fmaf(w, ldv(feat, isbf16, sb + 32), a1);
        a2 = fmaf(w, ldv(feat, isbf16, sb + 64), a2);
    }
    agg[gb]      = a0;
    agg[gb + 32] = a1;
    agg[gb + 64] = a2;
}

// ---------------------------------------------------------------------------
// GEMM + bias + ReLU: out[M,96] = relu(A[M,96] @ W[96,96] + b); A fp32.
// 256 threads = 8 colg x 32 rowg; 2 rows x 12 cols per thread => 64 rows/blk.
// grid 782 (vs 391 before): latency-bound fix. All W/A accesses via float4.
// ---------------------------------------------------------------------------
__global__ __launch_bounds__(256) void gemm_bias_relu_kernel(const float* A,
                                                             const void* W, const void* bias,
                                                             const int* flagF,
                                                             void* out, int outMode) {
    __shared__ float Ws[DIM * DIM];
    __shared__ float bs[DIM];
    int wBf16 = *flagF;
    int outBf16 = (outMode == 2) ? wBf16 : outMode;
    if (wBf16) {
        for (int i = threadIdx.x; i < DIM * DIM; i += 256)
            Ws[i] = bf16_to_f32(((const unsigned short*)W)[i]);
        if (threadIdx.x < DIM)
            bs[threadIdx.x] = bf16_to_f32(((const unsigned short*)bias)[threadIdx.x]);
    } else {
        const float4* W4 = (const float4*)W;
        float4* Ws4w = (float4*)Ws;
        for (int i = threadIdx.x; i < DIM * DIM / 4; i += 256) Ws4w[i] = W4[i];
        if (threadIdx.x < DIM) bs[threadIdx.x] = ((const float*)bias)[threadIdx.x];
    }
    __syncthreads();

    int colg = threadIdx.x & 7;   // 8 groups x 12 cols
    int rowg = threadIdx.x >> 3;  // 32 groups x 2 rows
    int row0 = blockIdx.x * 64 + rowg * 2;
    int c0 = colg * 12;           // c0*4 bytes = 48B -> 16B aligned

    float acc0[12], acc1[12];
    #pragma unroll
    for (int j = 0; j < 12; ++j) { acc0[j] = 0.0f; acc1[j] = 0.0f; }

    bool r0ok = (row0 < N_NODES);
    bool r1ok = (row0 + 1 < N_NODES);
    const float4* A0 = (const float4*)(A + (size_t)row0 * DIM);
    const float4* A1 = (const float4*)(A + (size_t)(row0 + 1) * DIM);
    const float4* Ws4 = (const float4*)Ws;
    const float4 z4 = make_float4(0.f, 0.f, 0.f, 0.f);

    for (int kc = 0; kc < DIM / 4; ++kc) {
        float4 a0 = r0ok ? A0[kc] : z4;
        float4 a1 = r1ok ? A1[kc] : z4;
        #pragma unroll
        for (int kk = 0; kk < 4; ++kk) {
            const float4* wrow = Ws4 + ((kc * 4 + kk) * DIM + c0) / 4;
            float4 w0 = wrow[0];
            float4 w1 = wrow[1];
            float4 w2 = wrow[2];
            float av0 = (kk == 0) ? a0.x : (kk == 1) ? a0.y : (kk == 2) ? a0.z : a0.w;
            float av1 = (kk == 0) ? a1.x : (kk == 1) ? a1.y : (kk == 2) ? a1.z : a1.w;
            acc0[0] = fmaf(av0, w0.x, acc0[0]);  acc1[0] = fmaf(av1, w0.x, acc1[0]);
            acc0[1] = fmaf(av0, w0.y, acc0[1]);  acc1[1] = fmaf(av1, w0.y, acc1[1]);
            acc0[2] = fmaf(av0, w0.z, acc0[2]);  acc1[2] = fmaf(av1, w0.z, acc1[2]);
            acc0[3] = fmaf(av0, w0.w, acc0[3]);  acc1[3] = fmaf(av1, w0.w, acc1[3]);
            acc0[4] = fmaf(av0, w1.x, acc0[4]);  acc1[4] = fmaf(av1, w1.x, acc1[4]);
            acc0[5] = fmaf(av0, w1.y, acc0[5]);  acc1[5] = fmaf(av1, w1.y, acc1[5]);
            acc0[6] = fmaf(av0, w1.z, acc0[6]);  acc1[6] = fmaf(av1, w1.z, acc1[6]);
            acc0[7] = fmaf(av0, w1.w, acc0[7]);  acc1[7] = fmaf(av1, w1.w, acc1[7]);
            acc0[8] = fmaf(av0, w2.x, acc0[8]);  acc1[8] = fmaf(av1, w2.x, acc1[8]);
            acc0[9] = fmaf(av0, w2.y, acc0[9]);  acc1[9] = fmaf(av1, w2.y, acc1[9]);
            acc0[10] = fmaf(av0, w2.z, acc0[10]); acc1[10] = fmaf(av1, w2.z, acc1[10]);
            acc0[11] = fmaf(av0, w2.w, acc0[11]); acc1[11] = fmaf(av1, w2.w, acc1[11]);
        }
    }

    #pragma unroll
    for (int r = 0; r < 2; ++r) {
        int row = row0 + r;
        if (row >= N_NODES) continue;
        float* accp = (r == 0) ? acc0 : acc1;
        int ob = row * DIM + c0;
        if (outBf16) {
            #pragma unroll
            for (int j = 0; j < 12; ++j) {
                float v = fmaxf(accp[j] + bs[c0 + j], 0.0f);
                ((unsigned short*)out)[ob + j] = f32_to_bf16_rne(v);
            }
        } else {
            float4 o[3];
            #pragma unroll
            for (int q = 0; q < 3; ++q) {
                o[q].x = fmaxf(accp[q * 4 + 0] + bs[c0 + q * 4 + 0], 0.0f);
                o[q].y = fmaxf(accp[q * 4 + 1] + bs[c0 + q * 4 + 1], 0.0f);
                o[q].z = fmaxf(accp[q * 4 + 2] + bs[c0 + q * 4 + 2], 0.0f);
                o[q].w = fmaxf(accp[q * 4 + 3] + bs[c0 + q * 4 + 3], 0.0f);
            }
            float4* op = (float4*)((float*)out + ob);
            op[0] = o[0]; op[1] = o[1]; op[2] = o[2];
        }
    }
}

// ---------------------------------------------------------------------------
extern "C" void kernel_launch(void* const* d_in, const int* in_sizes, int n_in,
                              void* d_out, int out_size, void* d_ws, size_t ws_size,
                              hipStream_t stream) {
    const void* x  = d_in[0];
    const void* ei = d_in[1];
    const void* W1 = d_in[2];
    const void* b1 = d_in[3];
    const void* W2 = d_in[4];
    const void* b2 = d_in[5];

    char* base = (char*)d_ws;
    size_t off = 0;
    auto carve = [&](size_t bytes) -> void* {
        void* p = base + off;
        off += (bytes + 255) & ~(size_t)255;
        return p;
    };
    int*   flagE     = (int*)carve(4);
    int*   flagF     = (int*)carve(4);
    int*   cnt       = (int*)carve((size_t)N_NODES * 4);
    int*   cursor    = (int*)carve((size_t)N_NODES * 4);
    int*   row_ptr   = (int*)carve((size_t)(N_NODES + 1) * 4);
    float* dinv      = (float*)carve((size_t)N_NODES * 4);
    int*   blockSums = (int*)carve((size_t)NBLK * 4);
    int*   blockOffs = (int*)carve((size_t)NBLK * 4);
    int*   csr_src   = (int*)carve((size_t)N_EDGES * 4);
    float* agg       = (float*)carve((size_t)FEAT_ELEMS * 4);
    // intermediate h: fp32 if workspace allows, else bf16 (function of ws_size only)
    int hBf16 = (ws_size != 0 && ws_size < off + (size_t)FEAT_ELEMS * 4 + 1024) ? 1 : 0;
    void* h = (void*)(base + off);

    const int ngrid = NBLK;                        // 196
    const int egrid = (N_EDGES + 255) / 256;       // 3125
    const int agrid = (N_NODES * 32 + 255) / 256;  // 6250
    const int ggrid = (N_NODES + 63) / 64;         // 782

    detect_edges_kernel<<<1, 64, 0, stream>>>((const unsigned int*)ei, flagE);
    detect_feat_kernel<<<1, 256, 0, stream>>>((const unsigned int*)x, flagF);

    zero_cnt_kernel<<<ngrid, 256, 0, stream>>>(cnt);
    count_kernel<<<egrid, 256, 0, stream>>>(ei, flagE, cnt);
    scan_blocksum_kernel<<<ngrid, 256, 0, stream>>>(cnt, blockSums);
    scan_offsets_kernel<<<1, 256, 0, stream>>>(blockSums, blockOffs, row_ptr);
    scan_apply_kernel<<<ngrid, 256, 0, stream>>>(cnt, blockOffs, row_ptr, cursor, dinv);
    fill_kernel<<<egrid, 256, 0, stream>>>(ei, flagE, cursor, csr_src);

    // ---- layer 1: agg = A_hat * x ; h = relu(agg @ W1 + b1) ----
    gather_kernel<<<agrid, 256, 0, stream>>>(x, flagF, 2, row_ptr, csr_src, dinv, agg);
    gemm_bias_relu_kernel<<<ggrid, 256, 0, stream>>>(agg, W1, b1, flagF, h, hBf16);

    // ---- layer 2: agg = A_hat * h ; out = relu(agg @ W2 + b2) ----
    gather_kernel<<<agrid, 256, 0, stream>>>(h, flagF, hBf16, row_ptr, csr_src, dinv, agg);
    gemm_bias_relu_kernel<<<ggrid, 256, 0, stream>>>(agg, W2, b2, flagF, d_out, 2);
}

// Round 8
// 278.549 us; speedup vs baseline: 2.6732x; 1.1571x over previous
//
#include <hip/hip_runtime.h>

#define N_NODES 50000
#define N_EDGES 800000
#define DIM 96
#define FEAT_ELEMS (N_NODES * DIM)
#define NBLK 196  // ceil(50000/256)

// ---------------------------------------------------------------------------
// bf16 helpers via raw bit ops
// ---------------------------------------------------------------------------
__device__ __forceinline__ float bf16_to_f32(unsigned short u) {
    unsigned int w = ((unsigned int)u) << 16;
    float f;
    __builtin_memcpy(&f, &w, 4);
    return f;
}
__device__ __forceinline__ unsigned short f32_to_bf16_rne(float f) {
    unsigned int w;
    __builtin_memcpy(&w, &f, 4);
    unsigned int r = (w + 0x7FFFu + ((w >> 16) & 1u)) >> 16;
    return (unsigned short)r;
}
__device__ __forceinline__ float ldv(const void* p, int isbf16, int idx) {
    if (isbf16) return bf16_to_f32(((const unsigned short*)p)[idx]);
    return ((const float*)p)[idx];
}

__device__ __forceinline__ int edge_at(const void* ep, int is64, int idx) {
    if (is64) return (int)((const long long*)ep)[idx];
    return ((const int*)ep)[idx];
}

// ---------------------------------------------------------------------------
// prolog: blocks [0,NBLK) zero cnt; block NBLK detects edge dtype (int64 =>
// odd 32-bit words all zero => flagE=1); block NBLK+1 detects float dtype of
// x (bf16 => bits14..7 is a N(0,1) bf16 exponent in [100,135] => flagF=1).
// ---------------------------------------------------------------------------
__global__ __launch_bounds__(256) void prolog_kernel(const unsigned int* edges,
                                                     const unsigned int* x,
                                                     int* flagE, int* flagF, int* cnt) {
    __shared__ unsigned int sh[256];
    int t = threadIdx.x;
    int b = blockIdx.x;
    if (b < NBLK) {
        int i = b * 256 + t;
        if (i < N_NODES) cnt[i] = 0;
        return;
    }
    if (b == NBLK) {
        if (t < 64) {
            unsigned int acc = 0;
            for (int k = 0; k < 4; ++k) {
                int idx = t * 4 + k;           // 0..255
                int pos = 1 + 2 * idx * 3109;  // odd words, max 1,585,591 < 1.6M
                acc |= edges[pos];
            }
            sh[t] = acc;
        }
        __syncthreads();
        if (t == 0) {
            unsigned int a = 0;
            for (int i = 0; i < 64; ++i) a |= sh[i];
            *flagE = (a == 0u) ? 1 : 0;
        }
        return;
    }
    // b == NBLK+1: feature dtype
    unsigned int w = x[t * 9000];  // max 2,295,000 < 2.4M words (bf16 interp)
    unsigned int e = (w >> 7) & 0xFFu;
    sh[t] = (e >= 100u && e <= 135u) ? 1u : 0u;
    __syncthreads();
    if (t == 0) {
        int c = 0;
        for (int i = 0; i < 256; ++i) c += (int)sh[i];
        *flagF = (c >= 128) ? 1 : 0;
    }
}

// ---------------------------------------------------------------------------
// CSR build: count in-degree at dst, 3-phase parallel scan, fill
// ---------------------------------------------------------------------------
__global__ __launch_bounds__(256) void count_kernel(const void* edges, const int* flagE,
                                                    int* cnt) {
    int e = blockIdx.x * 256 + threadIdx.x;
    if (e >= N_EDGES) return;
    int is64 = *flagE;
    int d = edge_at(edges, is64, N_EDGES + e);
    atomicAdd(&cnt[d], 1);
}

__global__ __launch_bounds__(256) void scan_blocksum_kernel(const int* cnt, int* blockSums) {
    __shared__ int sh[256];
    int i = blockIdx.x * 256 + threadIdx.x;
    sh[threadIdx.x] = (i < N_NODES) ? cnt[i] : 0;
    __syncthreads();
    for (int off = 128; off > 0; off >>= 1) {
        if (threadIdx.x < off) sh[threadIdx.x] += sh[threadIdx.x + off];
        __syncthreads();
    }
    if (threadIdx.x == 0) blockSums[blockIdx.x] = sh[0];
}

__global__ __launch_bounds__(256) void scan_offsets_kernel(const int* blockSums,
                                                           int* blockOffs, int* row_ptr) {
    __shared__ int sh[256];
    int t = threadIdx.x;
    int v = (t < NBLK) ? blockSums[t] : 0;
    sh[t] = v;
    __syncthreads();
    for (int off = 1; off < 256; off <<= 1) {
        int u = (t >= off) ? sh[t - off] : 0;
        __syncthreads();
        sh[t] += u;
        __syncthreads();
    }
    if (t < NBLK) blockOffs[t] = sh[t] - v;  // exclusive
    if (t == 255) row_ptr[N_NODES] = sh[255];
}

__global__ __launch_bounds__(256) void scan_apply_kernel(const int* cnt, const int* blockOffs,
                                                         int* row_ptr, int* cursor,
                                                         float* dinv) {
    __shared__ int sh[256];
    int t = threadIdx.x;
    int i = blockIdx.x * 256 + t;
    int c = (i < N_NODES) ? cnt[i] : 0;
    sh[t] = c;
    __syncthreads();
    for (int off = 1; off < 256; off <<= 1) {
        int u = (t >= off) ? sh[t - off] : 0;
        __syncthreads();
        sh[t] += u;
        __syncthreads();
    }
    if (i < N_NODES) {
        int excl = sh[t] - c + blockOffs[blockIdx.x];
        row_ptr[i] = excl;
        cursor[i]  = excl;
        dinv[i]    = rsqrtf((float)(c + 1));  // +1 self-loop
    }
}

__global__ __launch_bounds__(256) void fill_kernel(const void* edges, const int* flagE,
                                                   int* cursor, unsigned short* csr_src) {
    int e = blockIdx.x * 256 + threadIdx.x;
    if (e >= N_EDGES) return;
    int is64 = *flagE;
    int s = edge_at(edges, is64, e);
    int d = edge_at(edges, is64, N_EDGES + e);
    int pos = atomicAdd(&cursor[d], 1);
    csr_src[pos] = (unsigned short)s;
}

// ---------------------------------------------------------------------------
// convert features to bf16 (plain copy if already bf16): 4 elems/thread
// ---------------------------------------------------------------------------
__global__ __launch_bounds__(256) void convert_kernel(const void* x, const int* flagF,
                                                      unsigned short* xb) {
    int i4 = (blockIdx.x * 256 + threadIdx.x) * 4;
    if (i4 >= FEAT_ELEMS) return;
    int isbf16 = *flagF;
    ushort4 o;
    if (isbf16) {
        o = *(const ushort4*)((const unsigned short*)x + i4);
    } else {
        float4 v = *(const float4*)((const float*)x + i4);
        o.x = f32_to_bf16_rne(v.x);
        o.y = f32_to_bf16_rne(v.y);
        o.z = f32_to_bf16_rne(v.z);
        o.w = f32_to_bf16_rne(v.w);
    }
    *(ushort4*)(xb + i4) = o;
}

// ---------------------------------------------------------------------------
// Gather-aggregate (bf16 feat, fp32 accum):
//   agg[g,:] = dinv[g]^2*feat[g,:] + sum_{s in in(g)} dinv[s]*dinv[g]*feat[s,:]
// 16 lanes per node, 2 dims per lane per segment (3 segments of 32 dims),
// ushort2 loads (64B-contiguous per 16-lane group), float2 stores.
// ---------------------------------------------------------------------------
__global__ __launch_bounds__(256) void gather_kernel(const unsigned short* __restrict__ feat,
                                                     const int* __restrict__ row_ptr,
                                                     const unsigned short* __restrict__ csr_src,
                                                     const float* __restrict__ dinv,
                                                     float* __restrict__ agg) {
    int gid = blockIdx.x * 256 + threadIdx.x;
    int g = gid >> 4;
    int lane = gid & 15;
    if (g >= N_NODES) return;
    float di = dinv[g];
    int gb = g * DIM + lane * 2;
    ushort2 sv0 = *(const ushort2*)&feat[gb];
    ushort2 sv1 = *(const ushort2*)&feat[gb + 32];
    ushort2 sv2 = *(const ushort2*)&feat[gb + 64];
    float wself = di * di;
    float a0 = wself * bf16_to_f32(sv0.x), a1 = wself * bf16_to_f32(sv0.y);
    float a2 = wself * bf16_to_f32(sv1.x), a3 = wself * bf16_to_f32(sv1.y);
    float a4 = wself * bf16_to_f32(sv2.x), a5 = wself * bf16_to_f32(sv2.y);
    int e = row_ptr[g], e1 = row_ptr[g + 1];
    for (; e + 2 <= e1; e += 2) {
        int s0 = csr_src[e];
        int s1 = csr_src[e + 1];
        float w0 = dinv[s0] * di;
        float w1 = dinv[s1] * di;
        int b0 = s0 * DIM + lane * 2;
        int b1 = s1 * DIM + lane * 2;
        ushort2 p0 = *(const ushort2*)&feat[b0];
        ushort2 p1 = *(const ushort2*)&feat[b0 + 32];
        ushort2 p2 = *(const ushort2*)&feat[b0 + 64];
        ushort2 q0 = *(const ushort2*)&feat[b1];
        ushort2 q1 = *(const ushort2*)&feat[b1 + 32];
        ushort2 q2 = *(const ushort2*)&feat[b1 + 64];
        a0 = fmaf(w0, bf16_to_f32(p0.x), a0);  a1 = fmaf(w0, bf16_to_f32(p0.y), a1);
        a2 = fmaf(w0, bf16_to_f32(p1.x), a2);  a3 = fmaf(w0, bf16_to_f32(p1.y), a3);
        a4 = fmaf(w0, bf16_to_f32(p2.x), a4);  a5 = fmaf(w0, bf16_to_f32(p2.y), a5);
        a0 = fmaf(w1, bf16_to_f32(q0.x), a0);  a1 = fmaf(w1, bf16_to_f32(q0.y), a1);
        a2 = fmaf(w1, bf16_to_f32(q1.x), a2);  a3 = fmaf(w1, bf16_to_f32(q1.y), a3);
        a4 = fmaf(w1, bf16_to_f32(q2.x), a4);  a5 = fmaf(w1, bf16_to_f32(q2.y), a5);
    }
    if (e < e1) {
        int s = csr_src[e];
        float w = dinv[s] * di;
        int b0 = s * DIM + lane * 2;
        ushort2 p0 = *(const ushort2*)&feat[b0];
        ushort2 p1 = *(const ushort2*)&feat[b0 + 32];
        ushort2 p2 = *(const ushort2*)&feat[b0 + 64];
        a0 = fmaf(w, bf16_to_f32(p0.x), a0);  a1 = fmaf(w, bf16_to_f32(p0.y), a1);
        a2 = fmaf(w, bf16_to_f32(p1.x), a2);  a3 = fmaf(w, bf16_to_f32(p1.y), a3);
        a4 = fmaf(w, bf16_to_f32(p2.x), a4);  a5 = fmaf(w, bf16_to_f32(p2.y), a5);
    }
    *(float2*)&agg[gb]      = make_float2(a0, a1);
    *(float2*)&agg[gb + 32] = make_float2(a2, a3);
    *(float2*)&agg[gb + 64] = make_float2(a4, a5);
}

// ---------------------------------------------------------------------------
// GEMM + bias + ReLU: out[M,96] = relu(A[M,96] @ W[96,96] + b); A fp32.
// 256 threads = 8 colg x 32 rowg; 2 rows x 12 cols per thread => 64 rows/blk.
// outMode: 0=fp32, 1=bf16, 2=follow flagF
// ---------------------------------------------------------------------------
__global__ __launch_bounds__(256) void gemm_bias_relu_kernel(const float* A,
                                                             const void* W, const void* bias,
                                                             const int* flagF,
                                                             void* out, int outMode) {
    __shared__ float Ws[DIM * DIM];
    __shared__ float bs[DIM];
    int wBf16 = *flagF;
    int outBf16 = (outMode == 2) ? wBf16 : outMode;
    if (wBf16) {
        for (int i = threadIdx.x; i < DIM * DIM; i += 256)
            Ws[i] = bf16_to_f32(((const unsigned short*)W)[i]);
        if (threadIdx.x < DIM)
            bs[threadIdx.x] = bf16_to_f32(((const unsigned short*)bias)[threadIdx.x]);
    } else {
        const float4* W4 = (const float4*)W;
        float4* Ws4w = (float4*)Ws;
        for (int i = threadIdx.x; i < DIM * DIM / 4; i += 256) Ws4w[i] = W4[i];
        if (threadIdx.x < DIM) bs[threadIdx.x] = ((const float*)bias)[threadIdx.x];
    }
    __syncthreads();

    int colg = threadIdx.x & 7;   // 8 groups x 12 cols
    int rowg = threadIdx.x >> 3;  // 32 groups x 2 rows
    int row0 = blockIdx.x * 64 + rowg * 2;
    int c0 = colg * 12;

    float acc0[12], acc1[12];
    #pragma unroll
    for (int j = 0; j < 12; ++j) { acc0[j] = 0.0f; acc1[j] = 0.0f; }

    bool r0ok = (row0 < N_NODES);
    bool r1ok = (row0 + 1 < N_NODES);
    const float4* A0 = (const float4*)(A + (size_t)row0 * DIM);
    const float4* A1 = (const float4*)(A + (size_t)(row0 + 1) * DIM);
    const float4* Ws4 = (const float4*)Ws;
    const float4 z4 = make_float4(0.f, 0.f, 0.f, 0.f);

    for (int kc = 0; kc < DIM / 4; ++kc) {
        float4 a0 = r0ok ? A0[kc] : z4;
        float4 a1 = r1ok ? A1[kc] : z4;
        #pragma unroll
        for (int kk = 0; kk < 4; ++kk) {
            const float4* wrow = Ws4 + ((kc * 4 + kk) * DIM + c0) / 4;
            float4 w0 = wrow[0];
            float4 w1 = wrow[1];
            float4 w2 = wrow[2];
            float av0 = (kk == 0) ? a0.x : (kk == 1) ? a0.y : (kk == 2) ? a0.z : a0.w;
            float av1 = (kk == 0) ? a1.x : (kk == 1) ? a1.y : (kk == 2) ? a1.z : a1.w;
            acc0[0] = fmaf(av0, w0.x, acc0[0]);  acc1[0] = fmaf(av1, w0.x, acc1[0]);
            acc0[1] = fmaf(av0, w0.y, acc0[1]);  acc1[1] = fmaf(av1, w0.y, acc1[1]);
            acc0[2] = fmaf(av0, w0.z, acc0[2]);  acc1[2] = fmaf(av1, w0.z, acc1[2]);
            acc0[3] = fmaf(av0, w0.w, acc0[3]);  acc1[3] = fmaf(av1, w0.w, acc1[3]);
            acc0[4] = fmaf(av0, w1.x, acc0[4]);  acc1[4] = fmaf(av1, w1.x, acc1[4]);
            acc0[5] = fmaf(av0, w1.y, acc0[5]);  acc1[5] = fmaf(av1, w1.y, acc1[5]);
            acc0[6] = fmaf(av0, w1.z, acc0[6]);  acc1[6] = fmaf(av1, w1.z, acc1[6]);
            acc0[7] = fmaf(av0, w1.w, acc0[7]);  acc1[7] = fmaf(av1, w1.w, acc1[7]);
            acc0[8] = fmaf(av0, w2.x, acc0[8]);  acc1[8] = fmaf(av1, w2.x, acc1[8]);
            acc0[9] = fmaf(av0, w2.y, acc0[9]);  acc1[9] = fmaf(av1, w2.y, acc1[9]);
            acc0[10] = fmaf(av0, w2.z, acc0[10]); acc1[10] = fmaf(av1, w2.z, acc1[10]);
            acc0[11] = fmaf(av0, w2.w, acc0[11]); acc1[11] = fmaf(av1, w2.w, acc1[11]);
        }
    }

    #pragma unroll
    for (int r = 0; r < 2; ++r) {
        int row = row0 + r;
        if (row >= N_NODES) continue;
        float* accp = (r == 0) ? acc0 : acc1;
        int ob = row * DIM + c0;
        if (outBf16) {
            #pragma unroll
            for (int j = 0; j < 12; ++j) {
                float v = fmaxf(accp[j] + bs[c0 + j], 0.0f);
                ((unsigned short*)out)[ob + j] = f32_to_bf16_rne(v);
            }
        } else {
            float4 o[3];
            #pragma unroll
            for (int q = 0; q < 3; ++q) {
                o[q].x = fmaxf(accp[q * 4 + 0] + bs[c0 + q * 4 + 0], 0.0f);
                o[q].y = fmaxf(accp[q * 4 + 1] + bs[c0 + q * 4 + 1], 0.0f);
                o[q].z = fmaxf(accp[q * 4 + 2] + bs[c0 + q * 4 + 2], 0.0f);
                o[q].w = fmaxf(accp[q * 4 + 3] + bs[c0 + q * 4 + 3], 0.0f);
            }
            float4* op = (float4*)((float*)out + ob);
            op[0] = o[0]; op[1] = o[1]; op[2] = o[2];
        }
    }
}

// ---------------------------------------------------------------------------
extern "C" void kernel_launch(void* const* d_in, const int* in_sizes, int n_in,
                              void* d_out, int out_size, void* d_ws, size_t ws_size,
                              hipStream_t stream) {
    const void* x  = d_in[0];
    const void* ei = d_in[1];
    const void* W1 = d_in[2];
    const void* b1 = d_in[3];
    const void* W2 = d_in[4];
    const void* b2 = d_in[5];

    char* base = (char*)d_ws;
    size_t off = 0;
    auto carve = [&](size_t bytes) -> void* {
        void* p = base + off;
        off += (bytes + 255) & ~(size_t)255;
        return p;
    };
    int*            flagE     = (int*)carve(4);
    int*            flagF     = (int*)carve(4);
    int*            cnt       = (int*)carve((size_t)N_NODES * 4);
    int*            cursor    = (int*)carve((size_t)N_NODES * 4);
    int*            row_ptr   = (int*)carve((size_t)(N_NODES + 1) * 4);
    float*          dinv      = (float*)carve((size_t)N_NODES * 4);
    int*            blockSums = (int*)carve((size_t)NBLK * 4);
    int*            blockOffs = (int*)carve((size_t)NBLK * 4);
    unsigned short* csr_src   = (unsigned short*)carve((size_t)N_EDGES * 2);
    float*          agg       = (float*)carve((size_t)FEAT_ELEMS * 4);
    unsigned short* xb        = (unsigned short*)carve((size_t)FEAT_ELEMS * 2);
    unsigned short* h         = (unsigned short*)carve((size_t)FEAT_ELEMS * 2);

    const int egrid = (N_EDGES + 255) / 256;           // 3125
    const int cgrid = (FEAT_ELEMS / 4 + 255) / 256;    // 4688
    const int agrid = (N_NODES * 16 + 255) / 256;      // 3125
    const int ggrid = (N_NODES + 63) / 64;             // 782

    prolog_kernel<<<NBLK + 2, 256, 0, stream>>>((const unsigned int*)ei,
                                                (const unsigned int*)x, flagE, flagF, cnt);
    count_kernel<<<egrid, 256, 0, stream>>>(ei, flagE, cnt);
    scan_blocksum_kernel<<<NBLK, 256, 0, stream>>>(cnt, blockSums);
    scan_offsets_kernel<<<1, 256, 0, stream>>>(blockSums, blockOffs, row_ptr);
    scan_apply_kernel<<<NBLK, 256, 0, stream>>>(cnt, blockOffs, row_ptr, cursor, dinv);
    fill_kernel<<<egrid, 256, 0, stream>>>(ei, flagE, cursor, csr_src);
    convert_kernel<<<cgrid, 256, 0, stream>>>(x, flagF, xb);

    // ---- layer 1: agg = A_hat * x ; h = relu(agg @ W1 + b1) (bf16) ----
    gather_kernel<<<agrid, 256, 0, stream>>>(xb, row_ptr, csr_src, dinv, agg);
    gemm_bias_relu_kernel<<<ggrid, 256, 0, stream>>>(agg, W1, b1, flagF, h, 1);

    // ---- layer 2: agg = A_hat * h ; out = relu(agg @ W2 + b2) ----
    gather_kernel<<<agrid, 256, 0, stream>>>(h, row_ptr, csr_src, dinv, agg);
    gemm_bias_relu_kernel<<<ggrid, 256, 0, stream>>>(agg, W2, b2, flagF, d_out, 2);
}